// Round 8
// baseline (265.946 us; speedup 1.0000x reference)
//
#include <hip/hip_runtime.h>
#include <hip/hip_bf16.h>

#define NB 8192        // batch rows
#define M1T 139264     // NB + NB*16 rows in layer-1
#define SELFB 128      // NB/64 self blocks in l1
#define NFEAT 51200000 // 200000*256

typedef __attribute__((ext_vector_type(8))) short bf16x8;
typedef __attribute__((ext_vector_type(16))) float f32x16;
typedef __attribute__((ext_vector_type(4))) float f32x4;

__device__ __forceinline__ unsigned short f2b(float f) {
  union { float f; unsigned u; } v; v.f = f;
  unsigned r = v.u + 0x7fffu + ((v.u >> 16) & 1u);   // RNE
  return (unsigned short)(r >> 16);
}
__device__ __forceinline__ float b2f(unsigned u16) {
  union { unsigned u; float f; } v; v.u = u16 << 16;
  return v.f;
}
__device__ __forceinline__ uint4 pack8u(float a0, float a1, float a2, float a3,
                                        float a4, float a5, float a6, float a7) {
  uint4 v;
  v.x = (unsigned)f2b(a0) | ((unsigned)f2b(a1) << 16);
  v.y = (unsigned)f2b(a2) | ((unsigned)f2b(a3) << 16);
  v.z = (unsigned)f2b(a4) | ((unsigned)f2b(a5) << 16);
  v.w = (unsigned)f2b(a6) | ((unsigned)f2b(a7) << 16);
  return v;
}

#define GLDS16(g, l)                                                          \
  __builtin_amdgcn_global_load_lds(                                           \
      (const __attribute__((address_space(1))) unsigned int*)(const void*)(g),\
      (__attribute__((address_space(3))) unsigned int*)(void*)(l), 16, 0, 0)

// ---- kernel 0: weights fp32 -> bf16 in three layouts ----
// W1 -> W1s32 (per-32k-tile, 4-slot swizzle s^((n>>1)&3)) for sage_l1_bf32
//    -> W1s64 (per-64k-tile, 8-slot swizzle s^(n&7))       for fp32 fallback
// W2 -> W2s64 (per-64k-tile, 8-slot swizzle)               for sage_l2
__global__ void convert_w(const float* __restrict__ W1, const float* __restrict__ W2,
                          unsigned short* __restrict__ W1s32,
                          unsigned short* __restrict__ W1s64,
                          unsigned short* __restrict__ W2s64) {
  int i = blockIdx.x * 256 + threadIdx.x;  // 0..65535, one float4 each
  const float* W; int f4;
  if (i < 32768) { W = W1; f4 = i; }
  else           { W = W2; f4 = i - 32768; }
  int n  = (f4 * 4) >> 9;        // row 0..255
  int c0 = (f4 * 4) & 511;       // first col
  f32x4 v = *((const f32x4*)W + f4);
  ushort4 o;
  o.x = f2b(v[0]); o.y = f2b(v[1]); o.z = f2b(v[2]); o.w = f2b(v[3]);
  // 64k-tile layout (both W1s64 and W2s64)
  int kt64 = c0 >> 6, s8 = (c0 & 63) >> 3, e = c0 & 7;
  int off64 = kt64 * 16384 + n * 64 + ((s8 ^ (n & 7)) << 3) + e;
  if (i < 32768) {
    *(ushort4*)(W1s64 + off64) = o;
    int kt32 = c0 >> 5, s4 = (c0 >> 3) & 3;
    int off32 = kt32 * 8192 + n * 32 + (((s4 ^ ((n >> 1) & 3))) << 3) + e;
    *(ushort4*)(W1s32 + off32) = o;
  } else {
    *(ushort4*)(W2s64 + off64) = o;
  }
}

// ---- kernel 0b: feats fp32 -> bf16 table (row-major, 200000 x 256) ----
__global__ __launch_bounds__(256)
void conv_feats(const float* __restrict__ feats, unsigned short* __restrict__ featsb) {
  const int stride = gridDim.x * 256;
  for (size_t s = (size_t)blockIdx.x * 256 + threadIdx.x; s < NFEAT / 8; s += stride) {
    const f32x4* p = (const f32x4*)feats + s * 2;
    f32x4 x = __builtin_nontemporal_load(p);
    f32x4 y = __builtin_nontemporal_load(p + 1);
    *((uint4*)featsb + s) = pack8u(x[0], x[1], x[2], x[3], y[0], y[1], y[2], y[3]);
  }
}

// ---- layer 1 (bf16 table, BK=32, 48KB LDS -> 3 blocks/CU) ----
// relu([self || mean4(neigh2)] @ W1^T). BM=64, BN=256, 512 threads = 8 waves.
// A staged per 64-k PAIR (2 steps) with the proven 8-slot swizzle; B per
// 32-k step with 4-slot swizzle (pre-applied in convert_w; glds dest linear).
// One barrier per step; FIFO-exact vmcnt ladder.
__global__ __launch_bounds__(512, 6)
void sage_l1_bf32(const unsigned short* __restrict__ featsb,
                  const unsigned short* __restrict__ Wbs,   // W1s32
                  const int* __restrict__ batch_nodes,
                  const int* __restrict__ neigh1,
                  const int* __restrict__ neigh2,
                  unsigned short* __restrict__ A2)
{
  __shared__ __align__(16) unsigned short As[2][64 * 64];    // 2 x 8 KB (pair tiles)
  __shared__ __align__(16) unsigned short Bs[2][256 * 32];   // 2 x 16 KB
  const int tid = threadIdx.x;
  const int m0 = blockIdx.x * 64;
  const int w = tid >> 6, lane = tid & 63, l31 = lane & 31, lh = lane >> 5;
  const int mh = w & 1, nq = w >> 1;
  const int m = tid >> 3, slot = tid & 7;
  const int r = m0 + m;

  const int self = (r < NB) ? batch_nodes[r] : neigh1[r - NB];
  const int4 nb = *(const int4*)(neigh2 + (size_t)r * 4);
  const char* fb = (const char*)featsb;
  const unsigned so  = (unsigned)self * 512u + (unsigned)slot * 16u;
  const unsigned no0 = (unsigned)nb.x * 512u + (unsigned)slot * 16u;
  const unsigned no1 = (unsigned)nb.y * 512u + (unsigned)slot * 16u;
  const unsigned no2 = (unsigned)nb.z * 512u + (unsigned)slot * 16u;
  const unsigned no3 = (unsigned)nb.w * 512u + (unsigned)slot * 16u;
  const int arowC = mh * 32 + l31;
  const int n0C = nq * 64 + l31, n1C = n0C + 32;
  const int bsw0 = (n0C >> 1) & 3, bsw1 = (n1C >> 1) & 3;

  f32x16 acc0 = {}, acc1 = {};
  uint4 a0[4], a1[4];

  // pair P loads (identical to r6's per-64k loader)
  #define L1_LOADS(P, AR)                                                     \
    do { if ((P) < 4) {                                                       \
           AR[0] = *(const uint4*)(fb + so + (P) * 128);                      \
         } else {                                                             \
           const int _kb = ((P) - 4) * 128;                                   \
           AR[0] = *(const uint4*)(fb + no0 + _kb);                           \
           AR[1] = *(const uint4*)(fb + no1 + _kb);                           \
           AR[2] = *(const uint4*)(fb + no2 + _kb);                           \
           AR[3] = *(const uint4*)(fb + no3 + _kb);                           \
         } } while (0)

  #define L1_BISSUE(KT)                                                      \
    do { const unsigned short* _s = Wbs + (size_t)(KT) * 8192;               \
         unsigned short* _d = &Bs[(KT) & 1][0];                              \
         GLDS16(_s + (size_t)tid * 8, _d + tid * 8);                         \
         GLDS16(_s + (size_t)(512 + tid) * 8, _d + (512 + tid) * 8);         \
    } while (0)

  #define L1_CONV(P, AR, AV)                                                 \
    do { if ((P) < 4) { AV = AR[0]; }                                        \
         else {                                                              \
           float s0 = 0, s1 = 0, s2 = 0, s3 = 0, s4 = 0, s5 = 0, s6 = 0, s7 = 0; \
           _Pragma("unroll")                                                 \
           for (int _j = 0; _j < 4; ++_j) {                                  \
             s0 += b2f(AR[_j].x & 0xffffu); s1 += b2f(AR[_j].x >> 16);       \
             s2 += b2f(AR[_j].y & 0xffffu); s3 += b2f(AR[_j].y >> 16);       \
             s4 += b2f(AR[_j].z & 0xffffu); s5 += b2f(AR[_j].z >> 16);       \
             s6 += b2f(AR[_j].w & 0xffffu); s7 += b2f(AR[_j].w >> 16);       \
           }                                                                 \
           AV = pack8u(s0 * 0.25f, s1 * 0.25f, s2 * 0.25f, s3 * 0.25f,       \
                       s4 * 0.25f, s5 * 0.25f, s6 * 0.25f, s7 * 0.25f);      \
         } } while (0)

  #define L1_MFMA(KT)                                                        \
    do { const int _pa = ((KT) >> 1) & 1;                                    \
         _Pragma("unroll")                                                   \
         for (int _kk = 0; _kk < 2; ++_kk) {                                 \
           int _sA = ((KT) & 1) * 4 + _kk * 2 + lh;                          \
           int _sB = _kk * 2 + lh;                                           \
           bf16x8 _a  = *(const bf16x8*)(&As[_pa][arowC * 64 + ((_sA ^ (arowC & 7)) << 3)]); \
           bf16x8 _b0 = *(const bf16x8*)(&Bs[(KT) & 1][n0C * 32 + ((_sB ^ bsw0) << 3)]);     \
           bf16x8 _b1 = *(const bf16x8*)(&Bs[(KT) & 1][n1C * 32 + ((_sB ^ bsw1) << 3)]);     \
           acc0 = __builtin_amdgcn_mfma_f32_32x32x16_bf16(_a, _b0, acc0, 0, 0, 0);           \
           acc1 = __builtin_amdgcn_mfma_f32_32x32x16_bf16(_a, _b1, acc1, 0, 0, 0);           \
         } } while (0)

  // even step 2P: conv+write pair P, wait, barrier, issue B(KT+1) [+pair P+2]
  #define STEP_E(KT, P, AR, NCNT, DOLOAD)                                    \
    do { uint4 _av;                                                          \
         L1_CONV(P, AR, _av);                                                \
         *(uint4*)(&As[(P) & 1][m * 64 + ((slot ^ (m & 7)) << 3)]) = _av;    \
         asm volatile("s_waitcnt vmcnt(" #NCNT ") lgkmcnt(0)" ::: "memory"); \
         __builtin_amdgcn_s_barrier();                                       \
         L1_BISSUE((KT) + 1);                                                \
         if (DOLOAD) L1_LOADS((P) + 2, AR);                                  \
         __builtin_amdgcn_sched_barrier(0);                                  \
         __builtin_amdgcn_s_setprio(1);                                      \
         L1_MFMA(KT);                                                        \
         __builtin_amdgcn_s_setprio(0);                                      \
    } while (0)

  // odd step: wait, barrier, issue B(KT+1) (none at KT=15)
  #define STEP_O(KT, NCNT, DOB)                                              \
    do { asm volatile("s_waitcnt vmcnt(" #NCNT ") lgkmcnt(0)" ::: "memory"); \
         __builtin_amdgcn_s_barrier();                                       \
         if (DOB) L1_BISSUE((KT) + 1);                                       \
         __builtin_amdgcn_sched_barrier(0);                                  \
         __builtin_amdgcn_s_setprio(1);                                      \
         L1_MFMA(KT);                                                        \
         __builtin_amdgcn_s_setprio(0);                                      \
    } while (0)

  // prologue: queue = [A0(1), B0(2), A1(1)]
  L1_LOADS(0, a0);
  L1_BISSUE(0);
  L1_LOADS(1, a1);
  __builtin_amdgcn_sched_barrier(0);

  // FIFO-exact ladder (see derivation): [1,1,0,1,0,4,0,4,0,4,0,4,0,0,0,0]
  STEP_E(0, 0, a0, 1, 1);   // conv p0, load p2
  STEP_O(1, 1, 1);
  STEP_E(2, 1, a1, 0, 1);   // conv p1, load p3
  STEP_O(3, 1, 1);
  STEP_E(4, 2, a0, 0, 1);   // conv p2, load p4 (agg)
  STEP_O(5, 4, 1);
  STEP_E(6, 3, a1, 0, 1);   // conv p3, load p5
  STEP_O(7, 4, 1);
  STEP_E(8, 4, a0, 0, 1);   // conv p4, load p6
  STEP_O(9, 4, 1);
  STEP_E(10, 5, a1, 0, 1);  // conv p5, load p7
  STEP_O(11, 4, 1);
  STEP_E(12, 6, a0, 0, 0);  // conv p6
  STEP_O(13, 0, 1);
  STEP_E(14, 7, a1, 0, 0);  // conv p7
  STEP_O(15, 0, 0);

  #undef L1_LOADS
  #undef L1_BISSUE
  #undef L1_CONV
  #undef L1_MFMA
  #undef STEP_E
  #undef STEP_O

  if (blockIdx.x < SELFB) {
    #pragma unroll
    for (int q = 0; q < 16; ++q) {
      int row = m0 + mh * 32 + (q & 3) + 8 * (q >> 2) + 4 * lh;
      int col0 = nq * 64 + l31;
      float v0 = acc0[q], v1 = acc1[q];
      v0 = v0 > 0.f ? v0 : 0.f;
      v1 = v1 > 0.f ? v1 : 0.f;
      A2[(size_t)row * 512 + col0] = f2b(v0);
      A2[(size_t)row * 512 + col0 + 32] = f2b(v1);
    }
  } else {
    const int bi = blockIdx.x - SELFB;
    #pragma unroll
    for (int gi = 0; gi < 2; ++gi) {
      float sA = 0.f, sB = 0.f;
      #pragma unroll
      for (int q = gi * 8; q < gi * 8 + 8; ++q) {
        float v0 = acc0[q], v1 = acc1[q];
        sA += (v0 > 0.f ? v0 : 0.f);
        sB += (v1 > 0.f ? v1 : 0.f);
      }
      sA += __shfl_xor(sA, 32, 64);
      sB += __shfl_xor(sB, 32, 64);
      if (lh == 0) {
        int gr = bi * 4 + mh * 2 + gi;
        int col = 256 + nq * 64 + l31;
        A2[(size_t)gr * 512 + col] = f2b(sA * 0.0625f);
        A2[(size_t)gr * 512 + col + 32] = f2b(sB * 0.0625f);
      }
    }
  }
}

// ---- layer 1 (fp32 fallback, r5/r6-proven; uses W1s64) ----
__global__ __launch_bounds__(512, 4)
void sage_l1_f32(const float* __restrict__ feats,
                 const unsigned short* __restrict__ Wbs,    // W1s64
                 const int* __restrict__ batch_nodes,
                 const int* __restrict__ neigh1,
                 const int* __restrict__ neigh2,
                 unsigned short* __restrict__ A2)
{
  __shared__ __align__(16) unsigned short As[2][64 * 64];
  __shared__ __align__(16) unsigned short Bs[2][256 * 64];
  const int tid = threadIdx.x;
  const int m0 = blockIdx.x * 64;
  const int w = tid >> 6, lane = tid & 63, l31 = lane & 31, lh = lane >> 5;
  const int mh = w & 1, nq = w >> 1;
  const int m = tid >> 3, slot = tid & 7;
  const int r = m0 + m;

  const int self = (r < NB) ? batch_nodes[r] : neigh1[r - NB];
  const int4 nb = *(const int4*)(neigh2 + (size_t)r * 4);
  const char* fb = (const char*)feats;
  const unsigned so  = (unsigned)self * 1024u + (unsigned)slot * 32u;
  const unsigned no0 = (unsigned)nb.x * 1024u + (unsigned)slot * 32u;
  const unsigned no1 = (unsigned)nb.y * 1024u + (unsigned)slot * 32u;
  const unsigned no2 = (unsigned)nb.z * 1024u + (unsigned)slot * 32u;
  const unsigned no3 = (unsigned)nb.w * 1024u + (unsigned)slot * 32u;
  const int arowC = mh * 32 + l31;
  const int n0C = nq * 64 + l31, n1C = n0C + 32;

  f32x16 acc0 = {}, acc1 = {};
  f32x4 a0[8], a1[8];

  #define L1F_LOADS(KT, AR)                                                   \
    do { if ((KT) < 4) {                                                      \
           AR[0] = *(const f32x4*)(fb + so + (KT) * 256);                     \
           AR[1] = *(const f32x4*)(fb + so + (KT) * 256 + 16);                \
         } else {                                                             \
           const int _kb = ((KT) - 4) * 256;                                  \
           AR[0] = *(const f32x4*)(fb + no0 + _kb);                           \
           AR[1] = *(const f32x4*)(fb + no0 + _kb + 16);                      \
           AR[2] = *(const f32x4*)(fb + no1 + _kb);                           \
           AR[3] = *(const f32x4*)(fb + no1 + _kb + 16);                      \
           AR[4] = *(const f32x4*)(fb + no2 + _kb);                           \
           AR[5] = *(const f32x4*)(fb + no2 + _kb + 16);                      \
           AR[6] = *(const f32x4*)(fb + no3 + _kb);                           \
           AR[7] = *(const f32x4*)(fb + no3 + _kb + 16);                      \
         } } while (0)

  #define L1F_BISSUE(KT)                                                      \
    do { const unsigned short* _s = Wbs + (size_t)(KT) * 16384;               \
         unsigned short* _d = &Bs[(KT) & 1][0];                               \
         _Pragma("unroll")                                                    \
         for (int _q = 0; _q < 4; ++_q) {                                     \
           int _i = _q * 512 + tid;                                           \
           GLDS16(_s + (size_t)_i * 8, _d + _i * 8);                          \
         } } while (0)

  #define L1F_CONV(KT, AR, AV)                                                \
    do { if ((KT) < 4) {                                                      \
           AV = pack8u(AR[0][0], AR[0][1], AR[0][2], AR[0][3],                \
                       AR[1][0], AR[1][1], AR[1][2], AR[1][3]);               \
         } else {                                                             \
           float s0 = AR[0][0] + AR[2][0] + AR[4][0] + AR[6][0];              \
           float s1 = AR[0][1] + AR[2][1] + AR[4][1] + AR[6][1];              \
           float s2 = AR[0][2] + AR[2][2] + AR[4][2] + AR[6][2];              \
           float s3 = AR[0][3] + AR[2][3] + AR[4][3] + AR[6][3];              \
           float s4 = AR[1][0] + AR[3][0] + AR[5][0] + AR[7][0];              \
           float s5 = AR[1][1] + AR[3][1] + AR[5][1] + AR[7][1];              \
           float s6 = AR[1][2] + AR[3][2] + AR[5][2] + AR[7][2];              \
           float s7 = AR[1][3] + AR[3][3] + AR[5][3] + AR[7][3];              \
           AV = pack8u(s0 * 0.25f, s1 * 0.25f, s2 * 0.25f, s3 * 0.25f,        \
                       s4 * 0.25f, s5 * 0.25f, s6 * 0.25f, s7 * 0.25f);       \
         } } while (0)

  #define L1F_STEP(KT, AR, NCNT)                                              \
    do { uint4 _av;                                                           \
         L1F_CONV(KT, AR, _av);                                               \
         *(uint4*)(&As[(KT) & 1][m * 64 + ((slot ^ (m & 7)) << 3)]) = _av;    \
         asm volatile("s_waitcnt vmcnt(" #NCNT ") lgkmcnt(0)" ::: "memory");  \
         __builtin_amdgcn_s_barrier();                                        \
         if ((KT) < 7) L1F_BISSUE((KT) + 1);                                  \
         if ((KT) < 6) L1F_LOADS((KT) + 2, AR);                               \
         __builtin_amdgcn_sched_barrier(0);                                   \
         __builtin_amdgcn_s_setprio(1);                                       \
         _Pragma("unroll")                                                    \
         for (int _kk = 0; _kk < 4; ++_kk) {                                  \
           int _sl = _kk * 2 + lh;                                            \
           bf16x8 _a  = *(const bf16x8*)(&As[(KT) & 1][arowC * 64 + ((_sl ^ (arowC & 7)) << 3)]); \
           bf16x8 _b0 = *(const bf16x8*)(&Bs[(KT) & 1][n0C * 64 + ((_sl ^ (n0C & 7)) << 3)]);     \
           bf16x8 _b1 = *(const bf16x8*)(&Bs[(KT) & 1][n1C * 64 + ((_sl ^ (n1C & 7)) << 3)]);     \
           acc0 = __builtin_amdgcn_mfma_f32_32x32x16_bf16(_a, _b0, acc0, 0, 0, 0);                \
           acc1 = __builtin_amdgcn_mfma_f32_32x32x16_bf16(_a, _b1, acc1, 0, 0, 0);                \
         }                                                                    \
         __builtin_amdgcn_s_setprio(0);                                       \
    } while (0)

  L1F_LOADS(0, a0);
  L1F_BISSUE(0);
  L1F_LOADS(1, a1);
  __builtin_amdgcn_sched_barrier(0);

  L1F_STEP(0, a0, 2);
  L1F_STEP(1, a1, 2);
  L1F_STEP(2, a0, 2);
  L1F_STEP(3, a1, 8);
  L1F_STEP(4, a0, 8);
  L1F_STEP(5, a1, 8);
  L1F_STEP(6, a0, 8);
  L1F_STEP(7, a1, 0);

  #undef L1F_LOADS
  #undef L1F_BISSUE
  #undef L1F_CONV
  #undef L1F_STEP

  if (blockIdx.x < SELFB) {
    #pragma unroll
    for (int q = 0; q < 16; ++q) {
      int row = m0 + mh * 32 + (q & 3) + 8 * (q >> 2) + 4 * lh;
      int col0 = nq * 64 + l31;
      float v0 = acc0[q], v1 = acc1[q];
      v0 = v0 > 0.f ? v0 : 0.f;
      v1 = v1 > 0.f ? v1 : 0.f;
      A2[(size_t)row * 512 + col0] = f2b(v0);
      A2[(size_t)row * 512 + col0 + 32] = f2b(v1);
    }
  } else {
    const int bi = blockIdx.x - SELFB;
    #pragma unroll
    for (int gi = 0; gi < 2; ++gi) {
      float sA = 0.f, sB = 0.f;
      #pragma unroll
      for (int q = gi * 8; q < gi * 8 + 8; ++q) {
        float v0 = acc0[q], v1 = acc1[q];
        sA += (v0 > 0.f ? v0 : 0.f);
        sB += (v1 > 0.f ? v1 : 0.f);
      }
      sA += __shfl_xor(sA, 32, 64);
      sB += __shfl_xor(sB, 32, 64);
      if (lh == 0) {
        int gr = bi * 4 + mh * 2 + gi;
        int col = 256 + nq * 64 + l31;
        A2[(size_t)gr * 512 + col] = f2b(sA * 0.0625f);
        A2[(size_t)gr * 512 + col + 32] = f2b(sB * 0.0625f);
      }
    }
  }
}

// ---- layer 2: dense [8192 x 512](bf16) @ W2^T, relu, fp32 out ----
__global__ __launch_bounds__(256, 2)
void sage_l2(const unsigned short* __restrict__ A2,
             const unsigned short* __restrict__ Wbs,        // W2s64
             float* __restrict__ out)
{
  __shared__ __align__(16) unsigned short As[2][32 * 64];
  __shared__ __align__(16) unsigned short Bs[2][256 * 64];
  const int tid = threadIdx.x;
  const int m0 = blockIdx.x * 32;
  const int w = tid >> 6, lane = tid & 63, l31 = lane & 31, lh = lane >> 5;
  const int mA = tid >> 3, swA = tid & 7;
  const int arowC = l31;
  const int n0C = w * 64 + l31, n1C = n0C + 32;
  const unsigned short* aSrc = A2 + (size_t)(m0 + mA) * 512 + (swA ^ (mA & 7)) * 8;

  f32x16 acc0 = {}, acc1 = {};

  #define L2_STAGE(KT)                                                        \
    do { const unsigned short* _s = Wbs + (size_t)(KT) * 16384;               \
         unsigned short* _d = &Bs[(KT) & 1][0];                               \
         _Pragma("unroll")                                                    \
         for (int _q = 0; _q < 8; ++_q) {                                     \
           int _i = _q * 256 + tid;                                           \
           GLDS16(_s + (size_t)_i * 8, _d + _i * 8);                          \
         }                                                                    \
         GLDS16(aSrc + (KT) * 64, &As[(KT) & 1][mA * 64 + swA * 8]);          \
    } while (0)

  L2_STAGE(0);
  asm volatile("s_waitcnt vmcnt(0)" ::: "memory");
  __builtin_amdgcn_s_barrier();

  #pragma unroll
  for (int kt = 0; kt < 8; ++kt) {
    if (kt < 7) L2_STAGE(kt + 1);
    __builtin_amdgcn_s_setprio(1);
    #pragma unroll
    for (int kk = 0; kk < 4; ++kk) {
      int sl = kk * 2 + lh;
      bf16x8 a  = *(const bf16x8*)(&As[kt & 1][arowC * 64 + ((sl ^ (arowC & 7)) << 3)]);
      bf16x8 b0 = *(const bf16x8*)(&Bs[kt & 1][n0C * 64 + ((sl ^ (n0C & 7)) << 3)]);
      bf16x8 b1 = *(const bf16x8*)(&Bs[kt & 1][n1C * 64 + ((sl ^ (n1C & 7)) << 3)]);
      acc0 = __builtin_amdgcn_mfma_f32_32x32x16_bf16(a, b0, acc0, 0, 0, 0);
      acc1 = __builtin_amdgcn_mfma_f32_32x32x16_bf16(a, b1, acc1, 0, 0, 0);
    }
    __builtin_amdgcn_s_setprio(0);
    asm volatile("s_waitcnt vmcnt(0)" ::: "memory");
    __builtin_amdgcn_s_barrier();
  }
  #undef L2_STAGE

  #pragma unroll
  for (int q = 0; q < 16; ++q) {
    int row = m0 + (q & 3) + 8 * (q >> 2) + 4 * lh;
    float v0 = acc0[q], v1 = acc1[q];
    out[(size_t)row * 256 + n0C] = v0 > 0.f ? v0 : 0.f;
    out[(size_t)row * 256 + n1C] = v1 > 0.f ? v1 : 0.f;
  }
}

extern "C" void kernel_launch(void* const* d_in, const int* in_sizes, int n_in,
                              void* d_out, int out_size, void* d_ws, size_t ws_size,
                              hipStream_t stream) {
  const float* feats       = (const float*)d_in[0];
  const float* W1          = (const float*)d_in[1];
  const float* W2          = (const float*)d_in[2];
  const int*   batch_nodes = (const int*)d_in[3];
  const int*   neigh1      = (const int*)d_in[4];
  const int*   neigh2      = (const int*)d_in[5];
  float* out = (float*)d_out;

  unsigned short* W1s32  = (unsigned short*)d_ws;         // 131072 elems
  unsigned short* W1s64  = W1s32 + 131072;                // 131072 elems
  unsigned short* W2s64  = W1s64 + 131072;                // 131072 elems
  unsigned short* A2     = W2s64 + 131072;                // 8192*512 bf16 (8 MB)
  unsigned short* featsb = A2 + (size_t)NB * 512;         // 51.2M bf16 (102.4 MB)

  const size_t need = ((size_t)131072 * 3 + (size_t)NB * 512 + (size_t)NFEAT) * 2;

  hipLaunchKernelGGL(convert_w, dim3(256), dim3(256), 0, stream, W1, W2,
                     W1s32, W1s64, W2s64);
  if (ws_size >= need) {
    hipLaunchKernelGGL(conv_feats, dim3(3200), dim3(256), 0, stream, feats, featsb);
    hipLaunchKernelGGL(sage_l1_bf32, dim3(M1T / 64), dim3(512), 0, stream,
                       featsb, W1s32, batch_nodes, neigh1, neigh2, A2);
  } else {
    hipLaunchKernelGGL(sage_l1_f32, dim3(M1T / 64), dim3(512), 0, stream,
                       feats, W1s64, batch_nodes, neigh1, neigh2, A2);
  }
  hipLaunchKernelGGL(sage_l2, dim3(NB / 32), dim3(256), 0, stream, A2, W2s64, out);
}

// Round 9
// 141.075 us; speedup vs baseline: 1.8851x; 1.8851x over previous
//
#include <hip/hip_runtime.h>
#include <hip/hip_bf16.h>

#define NB 8192        // batch rows
#define M1T 139264     // NB + NB*16 rows in layer-1
#define SELFB 128      // NB/64 self blocks in l1
#define NFEAT 51200000 // 200000*256

typedef __attribute__((ext_vector_type(8))) short bf16x8;
typedef __attribute__((ext_vector_type(16))) float f32x16;
typedef __attribute__((ext_vector_type(4))) float f32x4;

__device__ __forceinline__ unsigned short f2b(float f) {
  union { float f; unsigned u; } v; v.f = f;
  unsigned r = v.u + 0x7fffu + ((v.u >> 16) & 1u);   // RNE
  return (unsigned short)(r >> 16);
}
__device__ __forceinline__ float b2f(unsigned u16) {
  union { unsigned u; float f; } v; v.u = u16 << 16;
  return v.f;
}
__device__ __forceinline__ uint4 pack8u(float a0, float a1, float a2, float a3,
                                        float a4, float a5, float a6, float a7) {
  uint4 v;
  v.x = (unsigned)f2b(a0) | ((unsigned)f2b(a1) << 16);
  v.y = (unsigned)f2b(a2) | ((unsigned)f2b(a3) << 16);
  v.z = (unsigned)f2b(a4) | ((unsigned)f2b(a5) << 16);
  v.w = (unsigned)f2b(a6) | ((unsigned)f2b(a7) << 16);
  return v;
}

#define GLDS16(g, l)                                                          \
  __builtin_amdgcn_global_load_lds(                                           \
      (const __attribute__((address_space(1))) unsigned int*)(const void*)(g),\
      (__attribute__((address_space(3))) unsigned int*)(void*)(l), 16, 0, 0)

// ---- kernel 0: weights fp32 -> bf16 in three layouts ----
__global__ void convert_w(const float* __restrict__ W1, const float* __restrict__ W2,
                          unsigned short* __restrict__ W1s32,
                          unsigned short* __restrict__ W1s64,
                          unsigned short* __restrict__ W2s64) {
  int i = blockIdx.x * 256 + threadIdx.x;  // 0..65535, one float4 each
  const float* W; int f4;
  if (i < 32768) { W = W1; f4 = i; }
  else           { W = W2; f4 = i - 32768; }
  int n  = (f4 * 4) >> 9;        // row 0..255
  int c0 = (f4 * 4) & 511;       // first col
  f32x4 v = *((const f32x4*)W + f4);
  ushort4 o;
  o.x = f2b(v[0]); o.y = f2b(v[1]); o.z = f2b(v[2]); o.w = f2b(v[3]);
  int kt64 = c0 >> 6, s8 = (c0 & 63) >> 3, e = c0 & 7;
  int off64 = kt64 * 16384 + n * 64 + ((s8 ^ (n & 7)) << 3) + e;
  if (i < 32768) {
    *(ushort4*)(W1s64 + off64) = o;
    int kt32 = c0 >> 5, s4 = (c0 >> 3) & 3;
    int off32 = kt32 * 8192 + n * 32 + (((s4 ^ ((n >> 1) & 3))) << 3) + e;
    *(ushort4*)(W1s32 + off32) = o;
  } else {
    *(ushort4*)(W2s64 + off64) = o;
  }
}

// ---- kernel 0b: feats fp32 -> bf16 table (row-major, 200000 x 256) ----
__global__ __launch_bounds__(256)
void conv_feats(const float* __restrict__ feats, unsigned short* __restrict__ featsb) {
  const int stride = gridDim.x * 256;
  for (size_t s = (size_t)blockIdx.x * 256 + threadIdx.x; s < NFEAT / 8; s += stride) {
    const f32x4* p = (const f32x4*)feats + s * 2;
    f32x4 x = __builtin_nontemporal_load(p);
    f32x4 y = __builtin_nontemporal_load(p + 1);
    *((uint4*)featsb + s) = pack8u(x[0], x[1], x[2], x[3], y[0], y[1], y[2], y[3]);
  }
}

// ---- layer 1 (bf16 table, BK=32, 48KB LDS -> 3 blocks/CU, depth-1 regs) ----
// relu([self || mean4(neigh2)] @ W1^T). BM=64, BN=256, 512 threads = 8 waves.
// A staged per 64-k PAIR with the 8-slot swizzle (depth-1: single a[4] buffer,
// 16 VGPR); B per 32-k step with 4-slot swizzle (pre-applied in convert_w).
// One barrier per step; FIFO-exact vmcnt ladder [0,1,0,1,0,1,0,4,...,4,0,0].
__global__ __launch_bounds__(512, 6)
void sage_l1_bf32(const unsigned short* __restrict__ featsb,
                  const unsigned short* __restrict__ Wbs,   // W1s32
                  const int* __restrict__ batch_nodes,
                  const int* __restrict__ neigh1,
                  const int* __restrict__ neigh2,
                  unsigned short* __restrict__ A2)
{
  __shared__ __align__(16) unsigned short As[2][64 * 64];    // 2 x 8 KB (pair tiles)
  __shared__ __align__(16) unsigned short Bs[2][256 * 32];   // 2 x 16 KB
  const int tid = threadIdx.x;
  const int m0 = blockIdx.x * 64;
  const int w = tid >> 6, lane = tid & 63, l31 = lane & 31, lh = lane >> 5;
  const int mh = w & 1, nq = w >> 1;
  const int m = tid >> 3, slot = tid & 7;
  const int r = m0 + m;

  const int self = (r < NB) ? batch_nodes[r] : neigh1[r - NB];
  const int4 nb = *(const int4*)(neigh2 + (size_t)r * 4);
  const char* fb = (const char*)featsb;
  const unsigned so  = (unsigned)self * 512u + (unsigned)slot * 16u;
  const unsigned no0 = (unsigned)nb.x * 512u + (unsigned)slot * 16u;
  const unsigned no1 = (unsigned)nb.y * 512u + (unsigned)slot * 16u;
  const unsigned no2 = (unsigned)nb.z * 512u + (unsigned)slot * 16u;
  const unsigned no3 = (unsigned)nb.w * 512u + (unsigned)slot * 16u;
  const int arowC = mh * 32 + l31;
  const int n0C = nq * 64 + l31, n1C = n0C + 32;

  f32x16 acc0 = {}, acc1 = {};
  uint4 a[4];

  #define L1_LOADS(P)                                                         \
    do { if ((P) < 4) {                                                       \
           a[0] = *(const uint4*)(fb + so + (P) * 128);                       \
         } else {                                                             \
           const int _kb = ((P) - 4) * 128;                                   \
           a[0] = *(const uint4*)(fb + no0 + _kb);                            \
           a[1] = *(const uint4*)(fb + no1 + _kb);                            \
           a[2] = *(const uint4*)(fb + no2 + _kb);                            \
           a[3] = *(const uint4*)(fb + no3 + _kb);                            \
         } } while (0)

  #define L1_BISSUE(KT)                                                      \
    do { const unsigned short* _s = Wbs + (size_t)(KT) * 8192;               \
         unsigned short* _d = &Bs[(KT) & 1][0];                              \
         GLDS16(_s + (size_t)tid * 8, _d + tid * 8);                         \
         GLDS16(_s + (size_t)(512 + tid) * 8, _d + (512 + tid) * 8);         \
    } while (0)

  #define L1_CONV(P, AV)                                                     \
    do { if ((P) < 4) { AV = a[0]; }                                         \
         else {                                                              \
           float s0 = 0, s1 = 0, s2 = 0, s3 = 0, s4 = 0, s5 = 0, s6 = 0, s7 = 0; \
           _Pragma("unroll")                                                 \
           for (int _j = 0; _j < 4; ++_j) {                                  \
             s0 += b2f(a[_j].x & 0xffffu); s1 += b2f(a[_j].x >> 16);         \
             s2 += b2f(a[_j].y & 0xffffu); s3 += b2f(a[_j].y >> 16);         \
             s4 += b2f(a[_j].z & 0xffffu); s5 += b2f(a[_j].z >> 16);         \
             s6 += b2f(a[_j].w & 0xffffu); s7 += b2f(a[_j].w >> 16);         \
           }                                                                 \
           AV = pack8u(s0 * 0.25f, s1 * 0.25f, s2 * 0.25f, s3 * 0.25f,       \
                       s4 * 0.25f, s5 * 0.25f, s6 * 0.25f, s7 * 0.25f);      \
         } } while (0)

  #define L1_MFMA(KT)                                                        \
    do { const int _pa = ((KT) >> 1) & 1;                                    \
         _Pragma("unroll")                                                   \
         for (int _kk = 0; _kk < 2; ++_kk) {                                 \
           int _sA = ((KT) & 1) * 4 + _kk * 2 + lh;                          \
           int _sB = _kk * 2 + lh;                                           \
           bf16x8 _a  = *(const bf16x8*)(&As[_pa][arowC * 64 + ((_sA ^ (arowC & 7)) << 3)]); \
           bf16x8 _b0 = *(const bf16x8*)(&Bs[(KT) & 1][n0C * 32 + ((_sB ^ ((n0C >> 1) & 3)) << 3)]); \
           bf16x8 _b1 = *(const bf16x8*)(&Bs[(KT) & 1][n1C * 32 + ((_sB ^ ((n1C >> 1) & 3)) << 3)]); \
           acc0 = __builtin_amdgcn_mfma_f32_32x32x16_bf16(_a, _b0, acc0, 0, 0, 0);           \
           acc1 = __builtin_amdgcn_mfma_f32_32x32x16_bf16(_a, _b1, acc1, 0, 0, 0);           \
         } } while (0)

  // even step 2P: conv pair P (drains A(P)), write As, wait B(KT), barrier,
  // issue B(KT+1) [+ pair P+1 loads], MFMA.
  #define STEP_E(KT, P, NCNT, DOLOAD)                                        \
    do { uint4 _av;                                                          \
         L1_CONV(P, _av);                                                    \
         *(uint4*)(&As[(P) & 1][m * 64 + ((slot ^ (m & 7)) << 3)]) = _av;    \
         asm volatile("s_waitcnt vmcnt(" #NCNT ") lgkmcnt(0)" ::: "memory"); \
         __builtin_amdgcn_s_barrier();                                       \
         L1_BISSUE((KT) + 1);                                                \
         if (DOLOAD) L1_LOADS((P) + 1);                                      \
         __builtin_amdgcn_sched_barrier(0);                                  \
         __builtin_amdgcn_s_setprio(1);                                      \
         L1_MFMA(KT);                                                        \
         __builtin_amdgcn_s_setprio(0);                                      \
    } while (0)

  // odd step: wait B(KT) (leaves the pending A pair), barrier, issue B(KT+1).
  #define STEP_O(KT, NCNT, DOB)                                              \
    do { asm volatile("s_waitcnt vmcnt(" #NCNT ") lgkmcnt(0)" ::: "memory"); \
         __builtin_amdgcn_s_barrier();                                       \
         if (DOB) L1_BISSUE((KT) + 1);                                       \
         __builtin_amdgcn_sched_barrier(0);                                  \
         __builtin_amdgcn_s_setprio(1);                                      \
         L1_MFMA(KT);                                                        \
         __builtin_amdgcn_s_setprio(0);                                      \
    } while (0)

  // prologue: queue = [A0(1), B0(2)]
  L1_LOADS(0);
  L1_BISSUE(0);
  __builtin_amdgcn_sched_barrier(0);

  STEP_E(0, 0, 0, 1);    // conv p0, load p1
  STEP_O(1, 1, 1);
  STEP_E(2, 1, 0, 1);    // conv p1, load p2
  STEP_O(3, 1, 1);
  STEP_E(4, 2, 0, 1);    // conv p2, load p3
  STEP_O(5, 1, 1);
  STEP_E(6, 3, 0, 1);    // conv p3, load p4 (agg)
  STEP_O(7, 4, 1);
  STEP_E(8, 4, 0, 1);    // conv p4, load p5
  STEP_O(9, 4, 1);
  STEP_E(10, 5, 0, 1);   // conv p5, load p6
  STEP_O(11, 4, 1);
  STEP_E(12, 6, 0, 1);   // conv p6, load p7
  STEP_O(13, 4, 1);
  STEP_E(14, 7, 0, 0);   // conv p7
  STEP_O(15, 0, 0);

  #undef L1_LOADS
  #undef L1_BISSUE
  #undef L1_CONV
  #undef L1_MFMA
  #undef STEP_E
  #undef STEP_O

  if (blockIdx.x < SELFB) {
    #pragma unroll
    for (int q = 0; q < 16; ++q) {
      int row = m0 + mh * 32 + (q & 3) + 8 * (q >> 2) + 4 * lh;
      int col0 = nq * 64 + l31;
      float v0 = acc0[q], v1 = acc1[q];
      v0 = v0 > 0.f ? v0 : 0.f;
      v1 = v1 > 0.f ? v1 : 0.f;
      A2[(size_t)row * 512 + col0] = f2b(v0);
      A2[(size_t)row * 512 + col0 + 32] = f2b(v1);
    }
  } else {
    const int bi = blockIdx.x - SELFB;
    #pragma unroll
    for (int gi = 0; gi < 2; ++gi) {
      float sA = 0.f, sB = 0.f;
      #pragma unroll
      for (int q = gi * 8; q < gi * 8 + 8; ++q) {
        float v0 = acc0[q], v1 = acc1[q];
        sA += (v0 > 0.f ? v0 : 0.f);
        sB += (v1 > 0.f ? v1 : 0.f);
      }
      sA += __shfl_xor(sA, 32, 64);
      sB += __shfl_xor(sB, 32, 64);
      if (lh == 0) {
        int gr = bi * 4 + mh * 2 + gi;
        int col = 256 + nq * 64 + l31;
        A2[(size_t)gr * 512 + col] = f2b(sA * 0.0625f);
        A2[(size_t)gr * 512 + col + 32] = f2b(sB * 0.0625f);
      }
    }
  }
}

// ---- layer 1 (fp32 fallback, r5-proven; uses W1s64) ----
__global__ __launch_bounds__(512, 4)
void sage_l1_f32(const float* __restrict__ feats,
                 const unsigned short* __restrict__ Wbs,    // W1s64
                 const int* __restrict__ batch_nodes,
                 const int* __restrict__ neigh1,
                 const int* __restrict__ neigh2,
                 unsigned short* __restrict__ A2)
{
  __shared__ __align__(16) unsigned short As[2][64 * 64];
  __shared__ __align__(16) unsigned short Bs[2][256 * 64];
  const int tid = threadIdx.x;
  const int m0 = blockIdx.x * 64;
  const int w = tid >> 6, lane = tid & 63, l31 = lane & 31, lh = lane >> 5;
  const int mh = w & 1, nq = w >> 1;
  const int m = tid >> 3, slot = tid & 7;
  const int r = m0 + m;

  const int self = (r < NB) ? batch_nodes[r] : neigh1[r - NB];
  const int4 nb = *(const int4*)(neigh2 + (size_t)r * 4);
  const char* fb = (const char*)feats;
  const unsigned so  = (unsigned)self * 1024u + (unsigned)slot * 32u;
  const unsigned no0 = (unsigned)nb.x * 1024u + (unsigned)slot * 32u;
  const unsigned no1 = (unsigned)nb.y * 1024u + (unsigned)slot * 32u;
  const unsigned no2 = (unsigned)nb.z * 1024u + (unsigned)slot * 32u;
  const unsigned no3 = (unsigned)nb.w * 1024u + (unsigned)slot * 32u;
  const int arowC = mh * 32 + l31;
  const int n0C = nq * 64 + l31, n1C = n0C + 32;

  f32x16 acc0 = {}, acc1 = {};
  f32x4 a0[8], a1[8];

  #define L1F_LOADS(KT, AR)                                                   \
    do { if ((KT) < 4) {                                                      \
           AR[0] = *(const f32x4*)(fb + so + (KT) * 256);                     \
           AR[1] = *(const f32x4*)(fb + so + (KT) * 256 + 16);                \
         } else {                                                             \
           const int _kb = ((KT) - 4) * 256;                                  \
           AR[0] = *(const f32x4*)(fb + no0 + _kb);                           \
           AR[1] = *(const f32x4*)(fb + no0 + _kb + 16);                      \
           AR[2] = *(const f32x4*)(fb + no1 + _kb);                           \
           AR[3] = *(const f32x4*)(fb + no1 + _kb + 16);                      \
           AR[4] = *(const f32x4*)(fb + no2 + _kb);                           \
           AR[5] = *(const f32x4*)(fb + no2 + _kb + 16);                      \
           AR[6] = *(const f32x4*)(fb + no3 + _kb);                           \
           AR[7] = *(const f32x4*)(fb + no3 + _kb + 16);                      \
         } } while (0)

  #define L1F_BISSUE(KT)                                                      \
    do { const unsigned short* _s = Wbs + (size_t)(KT) * 16384;               \
         unsigned short* _d = &Bs[(KT) & 1][0];                               \
         _Pragma("unroll")                                                    \
         for (int _q = 0; _q < 4; ++_q) {                                     \
           int _i = _q * 512 + tid;                                           \
           GLDS16(_s + (size_t)_i * 8, _d + _i * 8);                          \
         } } while (0)

  #define L1F_CONV(KT, AR, AV)                                                \
    do { if ((KT) < 4) {                                                      \
           AV = pack8u(AR[0][0], AR[0][1], AR[0][2], AR[0][3],                \
                       AR[1][0], AR[1][1], AR[1][2], AR[1][3]);               \
         } else {                                                             \
           float s0 = AR[0][0] + AR[2][0] + AR[4][0] + AR[6][0];              \
           float s1 = AR[0][1] + AR[2][1] + AR[4][1] + AR[6][1];              \
           float s2 = AR[0][2] + AR[2][2] + AR[4][2] + AR[6][2];              \
           float s3 = AR[0][3] + AR[2][3] + AR[4][3] + AR[6][3];              \
           float s4 = AR[1][0] + AR[3][0] + AR[5][0] + AR[7][0];              \
           float s5 = AR[1][1] + AR[3][1] + AR[5][1] + AR[7][1];              \
           float s6 = AR[1][2] + AR[3][2] + AR[5][2] + AR[7][2];              \
           float s7 = AR[1][3] + AR[3][3] + AR[5][3] + AR[7][3];              \
           AV = pack8u(s0 * 0.25f, s1 * 0.25f, s2 * 0.25f, s3 * 0.25f,        \
                       s4 * 0.25f, s5 * 0.25f, s6 * 0.25f, s7 * 0.25f);       \
         } } while (0)

  #define L1F_STEP(KT, AR, NCNT)                                              \
    do { uint4 _av;                                                           \
         L1F_CONV(KT, AR, _av);                                               \
         *(uint4*)(&As[(KT) & 1][m * 64 + ((slot ^ (m & 7)) << 3)]) = _av;    \
         asm volatile("s_waitcnt vmcnt(" #NCNT ") lgkmcnt(0)" ::: "memory");  \
         __builtin_amdgcn_s_barrier();                                        \
         if ((KT) < 7) L1F_BISSUE((KT) + 1);                                  \
         if ((KT) < 6) L1F_LOADS((KT) + 2, AR);                               \
         __builtin_amdgcn_sched_barrier(0);                                   \
         __builtin_amdgcn_s_setprio(1);                                       \
         _Pragma("unroll")                                                    \
         for (int _kk = 0; _kk < 4; ++_kk) {                                  \
           int _sl = _kk * 2 + lh;                                            \
           bf16x8 _a  = *(const bf16x8*)(&As[(KT) & 1][arowC * 64 + ((_sl ^ (arowC & 7)) << 3)]); \
           bf16x8 _b0 = *(const bf16x8*)(&Bs[(KT) & 1][n0C * 64 + ((_sl ^ (n0C & 7)) << 3)]);     \
           bf16x8 _b1 = *(const bf16x8*)(&Bs[(KT) & 1][n1C * 64 + ((_sl ^ (n1C & 7)) << 3)]);     \
           acc0 = __builtin_amdgcn_mfma_f32_32x32x16_bf16(_a, _b0, acc0, 0, 0, 0);                \
           acc1 = __builtin_amdgcn_mfma_f32_32x32x16_bf16(_a, _b1, acc1, 0, 0, 0);                \
         }                                                                    \
         __builtin_amdgcn_s_setprio(0);                                       \
    } while (0)

  L1F_LOADS(0, a0);
  L1F_BISSUE(0);
  L1F_LOADS(1, a1);
  __builtin_amdgcn_sched_barrier(0);

  L1F_STEP(0, a0, 2);
  L1F_STEP(1, a1, 2);
  L1F_STEP(2, a0, 2);
  L1F_STEP(3, a1, 8);
  L1F_STEP(4, a0, 8);
  L1F_STEP(5, a1, 8);
  L1F_STEP(6, a0, 8);
  L1F_STEP(7, a1, 0);

  #undef L1F_LOADS
  #undef L1F_BISSUE
  #undef L1F_CONV
  #undef L1F_STEP

  if (blockIdx.x < SELFB) {
    #pragma unroll
    for (int q = 0; q < 16; ++q) {
      int row = m0 + mh * 32 + (q & 3) + 8 * (q >> 2) + 4 * lh;
      int col0 = nq * 64 + l31;
      float v0 = acc0[q], v1 = acc1[q];
      v0 = v0 > 0.f ? v0 : 0.f;
      v1 = v1 > 0.f ? v1 : 0.f;
      A2[(size_t)row * 512 + col0] = f2b(v0);
      A2[(size_t)row * 512 + col0 + 32] = f2b(v1);
    }
  } else {
    const int bi = blockIdx.x - SELFB;
    #pragma unroll
    for (int gi = 0; gi < 2; ++gi) {
      float sA = 0.f, sB = 0.f;
      #pragma unroll
      for (int q = gi * 8; q < gi * 8 + 8; ++q) {
        float v0 = acc0[q], v1 = acc1[q];
        sA += (v0 > 0.f ? v0 : 0.f);
        sB += (v1 > 0.f ? v1 : 0.f);
      }
      sA += __shfl_xor(sA, 32, 64);
      sB += __shfl_xor(sB, 32, 64);
      if (lh == 0) {
        int gr = bi * 4 + mh * 2 + gi;
        int col = 256 + nq * 64 + l31;
        A2[(size_t)gr * 512 + col] = f2b(sA * 0.0625f);
        A2[(size_t)gr * 512 + col + 32] = f2b(sB * 0.0625f);
      }
    }
  }
}

// ---- layer 2: dense [8192 x 512](bf16) @ W2^T, relu, fp32 out ----
__global__ __launch_bounds__(256, 2)
void sage_l2(const unsigned short* __restrict__ A2,
             const unsigned short* __restrict__ Wbs,        // W2s64
             float* __restrict__ out)
{
  __shared__ __align__(16) unsigned short As[2][32 * 64];
  __shared__ __align__(16) unsigned short Bs[2][256 * 64];
  const int tid = threadIdx.x;
  const int m0 = blockIdx.x * 32;
  const int w = tid >> 6, lane = tid & 63, l31 = lane & 31, lh = lane >> 5;
  const int mA = tid >> 3, swA = tid & 7;
  const int arowC = l31;
  const int n0C = w * 64 + l31, n1C = n0C + 32;
  const unsigned short* aSrc = A2 + (size_t)(m0 + mA) * 512 + (swA ^ (mA & 7)) * 8;

  f32x16 acc0 = {}, acc1 = {};

  #define L2_STAGE(KT)                                                        \
    do { const unsigned short* _s = Wbs + (size_t)(KT) * 16384;               \
         unsigned short* _d = &Bs[(KT) & 1][0];                               \
         _Pragma("unroll")                                                    \
         for (int _q = 0; _q < 8; ++_q) {                                     \
           int _i = _q * 256 + tid;                                           \
           GLDS16(_s + (size_t)_i * 8, _d + _i * 8);                          \
         }                                                                    \
         GLDS16(aSrc + (KT) * 64, &As[(KT) & 1][mA * 64 + swA * 8]);          \
    } while (0)

  L2_STAGE(0);
  asm volatile("s_waitcnt vmcnt(0)" ::: "memory");
  __builtin_amdgcn_s_barrier();

  #pragma unroll
  for (int kt = 0; kt < 8; ++kt) {
    if (kt < 7) L2_STAGE(kt + 1);
    __builtin_amdgcn_s_setprio(1);
    #pragma unroll
    for (int kk = 0; kk < 4; ++kk) {
      int sl = kk * 2 + lh;
      bf16x8 a  = *(const bf16x8*)(&As[kt & 1][arowC * 64 + ((sl ^ (arowC & 7)) << 3)]);
      bf16x8 b0 = *(const bf16x8*)(&Bs[kt & 1][n0C * 64 + ((sl ^ (n0C & 7)) << 3)]);
      bf16x8 b1 = *(const bf16x8*)(&Bs[kt & 1][n1C * 64 + ((sl ^ (n1C & 7)) << 3)]);
      acc0 = __builtin_amdgcn_mfma_f32_32x32x16_bf16(a, b0, acc0, 0, 0, 0);
      acc1 = __builtin_amdgcn_mfma_f32_32x32x16_bf16(a, b1, acc1, 0, 0, 0);
    }
    __builtin_amdgcn_s_setprio(0);
    asm volatile("s_waitcnt vmcnt(0)" ::: "memory");
    __builtin_amdgcn_s_barrier();
  }
  #undef L2_STAGE

  #pragma unroll
  for (int q = 0; q < 16; ++q) {
    int row = m0 + (q & 3) + 8 * (q >> 2) + 4 * lh;
    float v0 = acc0[q], v1 = acc1[q];
    out[(size_t)row * 256 + n0C] = v0 > 0.f ? v0 : 0.f;
    out[(size_t)row * 256 + n1C] = v1 > 0.f ? v1 : 0.f;
  }
}

extern "C" void kernel_launch(void* const* d_in, const int* in_sizes, int n_in,
                              void* d_out, int out_size, void* d_ws, size_t ws_size,
                              hipStream_t stream) {
  const float* feats       = (const float*)d_in[0];
  const float* W1          = (const float*)d_in[1];
  const float* W2          = (const float*)d_in[2];
  const int*   batch_nodes = (const int*)d_in[3];
  const int*   neigh1      = (const int*)d_in[4];
  const int*   neigh2      = (const int*)d_in[5];
  float* out = (float*)d_out;

  unsigned short* W1s32  = (unsigned short*)d_ws;         // 131072 elems
  unsigned short* W1s64  = W1s32 + 131072;                // 131072 elems
  unsigned short* W2s64  = W1s64 + 131072;                // 131072 elems
  unsigned short* A2     = W2s64 + 131072;                // 8192*512 bf16 (8 MB)
  unsigned short* featsb = A2 + (size_t)NB * 512;         // 51.2M bf16 (102.4 MB)

  const size_t need = ((size_t)131072 * 3 + (size_t)NB * 512 + (size_t)NFEAT) * 2;

  hipLaunchKernelGGL(convert_w, dim3(256), dim3(256), 0, stream, W1, W2,
                     W1s32, W1s64, W2s64);
  if (ws_size >= need) {
    hipLaunchKernelGGL(conv_feats, dim3(3200), dim3(256), 0, stream, feats, featsb);
    hipLaunchKernelGGL(sage_l1_bf32, dim3(M1T / 64), dim3(512), 0, stream,
                       featsb, W1s32, batch_nodes, neigh1, neigh2, A2);
  } else {
    hipLaunchKernelGGL(sage_l1_f32, dim3(M1T / 64), dim3(512), 0, stream,
                       feats, W1s64, batch_nodes, neigh1, neigh2, A2);
  }
  hipLaunchKernelGGL(sage_l2, dim3(NB / 32), dim3(256), 0, stream, A2, W2s64, out);
}

// Round 10
// 126.910 us; speedup vs baseline: 2.0956x; 1.1116x over previous
//
#include <hip/hip_runtime.h>
#include <hip/hip_bf16.h>

#define NB 8192        // batch rows
#define M1T 139264     // NB + NB*16 rows in layer-1
#define SELFB 128      // NB/64 self blocks in l1

typedef __attribute__((ext_vector_type(8))) short bf16x8;
typedef __attribute__((ext_vector_type(16))) float f32x16;

__device__ __forceinline__ unsigned short f2b(float f) {
  union { float f; unsigned u; } v; v.f = f;
  unsigned r = v.u + 0x7fffu + ((v.u >> 16) & 1u);   // RNE
  return (unsigned short)(r >> 16);
}
__device__ __forceinline__ uint4 pack8u(float a0, float a1, float a2, float a3,
                                        float a4, float a5, float a6, float a7) {
  uint4 v;
  v.x = (unsigned)f2b(a0) | ((unsigned)f2b(a1) << 16);
  v.y = (unsigned)f2b(a2) | ((unsigned)f2b(a3) << 16);
  v.z = (unsigned)f2b(a4) | ((unsigned)f2b(a5) << 16);
  v.w = (unsigned)f2b(a6) | ((unsigned)f2b(a7) << 16);
  return v;
}

#define GLDS16(g, l)                                                          \
  __builtin_amdgcn_global_load_lds(                                           \
      (const __attribute__((address_space(1))) unsigned int*)(const void*)(g),\
      (__attribute__((address_space(3))) unsigned int*)(void*)(l), 16, 0, 0)

// ---- kernel 0: W1/W2 fp32 -> bf16, PRE-SWIZZLED per-kt tile layout ----
__global__ void convert_w(const float* __restrict__ W1, const float* __restrict__ W2,
                          unsigned short* __restrict__ W1s, unsigned short* __restrict__ W2s) {
  int i = blockIdx.x * 256 + threadIdx.x;  // 0..65535, one float4 each
  const float* W; unsigned short* out; int f4;
  if (i < 32768) { W = W1; out = W1s; f4 = i; }
  else           { W = W2; out = W2s; f4 = i - 32768; }
  int n  = (f4 * 4) >> 9;
  int c0 = (f4 * 4) & 511;
  int kt = c0 >> 6;
  int slot = (c0 & 63) >> 3;
  int e  = c0 & 7;               // 0 or 4
  int sw = slot ^ (n & 7);
  float4 v = *((const float4*)W + f4);
  ushort4 o;
  o.x = f2b(v.x); o.y = f2b(v.y); o.z = f2b(v.z); o.w = f2b(v.w);
  *(ushort4*)(out + kt * 16384 + n * 64 + sw * 8 + e) = o;
}

// ---- layer 1: relu([self || mean4(neigh2)] @ W1^T) ----
// Self blocks (bi < 128) write rows into A2 cols 0..255.
// Neighbor blocks reduce 16-row groups in-register -> A2 cols 256..511.
__global__ __launch_bounds__(512, 4)
void sage_l1(const float* __restrict__ feats,
             const unsigned short* __restrict__ Wbs,
             const int* __restrict__ batch_nodes,
             const int* __restrict__ neigh1,
             const int* __restrict__ neigh2,
             unsigned short* __restrict__ A2)
{
  __shared__ __align__(16) unsigned short As[2][64 * 64];    // 2 x 8 KB
  __shared__ __align__(16) unsigned short Bs[2][256 * 64];   // 2 x 32 KB
  const int tid = threadIdx.x;
  const int m0 = blockIdx.x * 64;
  const int w = tid >> 6, lane = tid & 63, l31 = lane & 31, lh = lane >> 5;
  const int mh = w & 1, nq = w >> 1;
  const int m = tid >> 3, slot = tid & 7;
  const int r = m0 + m;

  const int self = (r < NB) ? batch_nodes[r] : neigh1[r - NB];
  const int4 nb = *(const int4*)(neigh2 + (size_t)r * 4);
  const char* fb = (const char*)feats;
  const unsigned so  = (unsigned)self * 1024u + (unsigned)slot * 32u;
  const unsigned no0 = (unsigned)nb.x * 1024u + (unsigned)slot * 32u;
  const unsigned no1 = (unsigned)nb.y * 1024u + (unsigned)slot * 32u;
  const unsigned no2 = (unsigned)nb.z * 1024u + (unsigned)slot * 32u;
  const unsigned no3 = (unsigned)nb.w * 1024u + (unsigned)slot * 32u;
  const int arowC = mh * 32 + l31;
  const int n0C = nq * 64 + l31, n1C = n0C + 32;

  f32x16 acc0 = {}, acc1 = {};
  float4 a0[8], a1[8];

  #define L1_LOADS(KT, AR)                                                    \
    do { if ((KT) < 4) {                                                      \
           AR[0] = *(const float4*)(fb + so + (KT) * 256);                    \
           AR[1] = *(const float4*)(fb + so + (KT) * 256 + 16);               \
         } else {                                                             \
           const int _kb = ((KT) - 4) * 256;                                  \
           AR[0] = *(const float4*)(fb + no0 + _kb);                          \
           AR[1] = *(const float4*)(fb + no0 + _kb + 16);                     \
           AR[2] = *(const float4*)(fb + no1 + _kb);                          \
           AR[3] = *(const float4*)(fb + no1 + _kb + 16);                     \
           AR[4] = *(const float4*)(fb + no2 + _kb);                          \
           AR[5] = *(const float4*)(fb + no2 + _kb + 16);                     \
           AR[6] = *(const float4*)(fb + no3 + _kb);                          \
           AR[7] = *(const float4*)(fb + no3 + _kb + 16);                     \
         } } while (0)

  #define L1_BISSUE(KT)                                                       \
    do { const unsigned short* _s = Wbs + (size_t)(KT) * 16384;               \
         unsigned short* _d = &Bs[(KT) & 1][0];                               \
         _Pragma("unroll")                                                    \
         for (int _q = 0; _q < 4; ++_q) {                                     \
           int _i = _q * 512 + tid;                                           \
           GLDS16(_s + (size_t)_i * 8, _d + _i * 8);                          \
         } } while (0)

  #define L1_CONV(KT, AR, AV)                                                 \
    do { if ((KT) < 4) {                                                      \
           AV = pack8u(AR[0].x, AR[0].y, AR[0].z, AR[0].w,                    \
                       AR[1].x, AR[1].y, AR[1].z, AR[1].w);                   \
         } else {                                                             \
           float s0 = AR[0].x + AR[2].x + AR[4].x + AR[6].x;                  \
           float s1 = AR[0].y + AR[2].y + AR[4].y + AR[6].y;                  \
           float s2 = AR[0].z + AR[2].z + AR[4].z + AR[6].z;                  \
           float s3 = AR[0].w + AR[2].w + AR[4].w + AR[6].w;                  \
           float s4 = AR[1].x + AR[3].x + AR[5].x + AR[7].x;                  \
           float s5 = AR[1].y + AR[3].y + AR[5].y + AR[7].y;                  \
           float s6 = AR[1].z + AR[3].z + AR[5].z + AR[7].z;                  \
           float s7 = AR[1].w + AR[3].w + AR[5].w + AR[7].w;                  \
           AV = pack8u(s0 * 0.25f, s1 * 0.25f, s2 * 0.25f, s3 * 0.25f,       \
                       s4 * 0.25f, s5 * 0.25f, s6 * 0.25f, s7 * 0.25f);      \
         } } while (0)

  // One K-step. Queue entering: [A(KT), B(KT), A(KT+1)].
  #define L1_STEP(KT, AR, NCNT)                                               \
    do { uint4 _av;                                                           \
         L1_CONV(KT, AR, _av);   /* auto-wait drains A(KT), leaves B,A+1 */   \
         *(uint4*)(&As[(KT) & 1][m * 64 + ((slot ^ (m & 7)) << 3)]) = _av;    \
         asm volatile("s_waitcnt vmcnt(" #NCNT ") lgkmcnt(0)" ::: "memory");  \
         __builtin_amdgcn_s_barrier();                                        \
         if ((KT) < 7) L1_BISSUE((KT) + 1);                                   \
         if ((KT) < 6) L1_LOADS((KT) + 2, AR);                                \
         __builtin_amdgcn_sched_barrier(0);                                   \
         __builtin_amdgcn_s_setprio(1);                                       \
         _Pragma("unroll")                                                    \
         for (int _kk = 0; _kk < 4; ++_kk) {                                  \
           int _sl = _kk * 2 + lh;                                            \
           bf16x8 _a  = *(const bf16x8*)(&As[(KT) & 1][arowC * 64 + ((_sl ^ (arowC & 7)) << 3)]); \
           bf16x8 _b0 = *(const bf16x8*)(&Bs[(KT) & 1][n0C * 64 + ((_sl ^ (n0C & 7)) << 3)]);     \
           bf16x8 _b1 = *(const bf16x8*)(&Bs[(KT) & 1][n1C * 64 + ((_sl ^ (n1C & 7)) << 3)]);     \
           acc0 = __builtin_amdgcn_mfma_f32_32x32x16_bf16(_a, _b0, acc0, 0, 0, 0);                \
           acc1 = __builtin_amdgcn_mfma_f32_32x32x16_bf16(_a, _b1, acc1, 0, 0, 0);                \
         }                                                                    \
         __builtin_amdgcn_s_setprio(0);                                       \
    } while (0)

  // prologue: queue = [A(0), B(0), A(1)]
  L1_LOADS(0, a0);
  L1_BISSUE(0);
  L1_LOADS(1, a1);
  __builtin_amdgcn_sched_barrier(0);

  L1_STEP(0, a0, 2);
  L1_STEP(1, a1, 2);
  L1_STEP(2, a0, 2);
  L1_STEP(3, a1, 8);
  L1_STEP(4, a0, 8);
  L1_STEP(5, a1, 8);
  L1_STEP(6, a0, 8);
  L1_STEP(7, a1, 0);

  #undef L1_LOADS
  #undef L1_BISSUE
  #undef L1_CONV
  #undef L1_STEP

  if (blockIdx.x < SELFB) {
    // self rows -> A2 cols [0,256), row-major stride 512
    #pragma unroll
    for (int q = 0; q < 16; ++q) {
      int row = m0 + mh * 32 + (q & 3) + 8 * (q >> 2) + 4 * lh;
      int col0 = nq * 64 + l31;
      float v0 = acc0[q], v1 = acc1[q];
      v0 = v0 > 0.f ? v0 : 0.f;
      v1 = v1 > 0.f ? v1 : 0.f;
      A2[(size_t)row * 512 + col0] = f2b(v0);
      A2[(size_t)row * 512 + col0 + 32] = f2b(v1);
    }
  } else {
    // neighbor rows: relu then mean over 16-row groups -> A2 cols [256,512)
    const int bi = blockIdx.x - SELFB;
    #pragma unroll
    for (int gi = 0; gi < 2; ++gi) {
      float sA = 0.f, sB = 0.f;
      #pragma unroll
      for (int q = gi * 8; q < gi * 8 + 8; ++q) {
        float v0 = acc0[q], v1 = acc1[q];
        sA += (v0 > 0.f ? v0 : 0.f);
        sB += (v1 > 0.f ? v1 : 0.f);
      }
      sA += __shfl_xor(sA, 32, 64);   // combine lh halves -> full 16-row sum
      sB += __shfl_xor(sB, 32, 64);
      if (lh == 0) {
        int gr = bi * 4 + mh * 2 + gi;
        int col = 256 + nq * 64 + l31;
        A2[(size_t)gr * 512 + col] = f2b(sA * 0.0625f);
        A2[(size_t)gr * 512 + col + 32] = f2b(sB * 0.0625f);
      }
    }
  }
}

// ---- layer 2: dense [8192 x 512](bf16) @ W2^T, relu, fp32 out ----
// BM=32 -> 256 blocks, 256 threads = 4 waves; wave w owns cols w*64.
__global__ __launch_bounds__(256, 2)
void sage_l2(const unsigned short* __restrict__ A2,
             const unsigned short* __restrict__ Wbs,
             float* __restrict__ out)
{
  __shared__ __align__(16) unsigned short As[2][32 * 64];    // 2 x 4 KB
  __shared__ __align__(16) unsigned short Bs[2][256 * 64];   // 2 x 32 KB
  const int tid = threadIdx.x;
  const int m0 = blockIdx.x * 32;
  const int w = tid >> 6, lane = tid & 63, l31 = lane & 31, lh = lane >> 5;
  const int mA = tid >> 3, swA = tid & 7;
  const int arowC = l31;
  const int n0C = w * 64 + l31, n1C = n0C + 32;
  // pre-swizzled A source: LDS slot (mA, swA) holds data for slot swA^(mA&7)
  const unsigned short* aSrc = A2 + (size_t)(m0 + mA) * 512 + (swA ^ (mA & 7)) * 8;

  f32x16 acc0 = {}, acc1 = {};

  #define L2_STAGE(KT)                                                        \
    do { const unsigned short* _s = Wbs + (size_t)(KT) * 16384;               \
         unsigned short* _d = &Bs[(KT) & 1][0];                               \
         _Pragma("unroll")                                                    \
         for (int _q = 0; _q < 8; ++_q) {                                     \
           int _i = _q * 256 + tid;                                           \
           GLDS16(_s + (size_t)_i * 8, _d + _i * 8);                          \
         }                                                                    \
         GLDS16(aSrc + (KT) * 64, &As[(KT) & 1][mA * 64 + swA * 8]);          \
    } while (0)

  L2_STAGE(0);
  asm volatile("s_waitcnt vmcnt(0)" ::: "memory");
  __builtin_amdgcn_s_barrier();

  #pragma unroll
  for (int kt = 0; kt < 8; ++kt) {
    if (kt < 7) L2_STAGE(kt + 1);                // into buf^1, safe vs reads of buf
    __builtin_amdgcn_s_setprio(1);
    #pragma unroll
    for (int kk = 0; kk < 4; ++kk) {
      int sl = kk * 2 + lh;
      bf16x8 a  = *(const bf16x8*)(&As[kt & 1][arowC * 64 + ((sl ^ (arowC & 7)) << 3)]);
      bf16x8 b0 = *(const bf16x8*)(&Bs[kt & 1][n0C * 64 + ((sl ^ (n0C & 7)) << 3)]);
      bf16x8 b1 = *(const bf16x8*)(&Bs[kt & 1][n1C * 64 + ((sl ^ (n1C & 7)) << 3)]);
      acc0 = __builtin_amdgcn_mfma_f32_32x32x16_bf16(a, b0, acc0, 0, 0, 0);
      acc1 = __builtin_amdgcn_mfma_f32_32x32x16_bf16(a, b1, acc1, 0, 0, 0);
    }
    __builtin_amdgcn_s_setprio(0);
    asm volatile("s_waitcnt vmcnt(0)" ::: "memory");
    __builtin_amdgcn_s_barrier();
  }
  #undef L2_STAGE

  #pragma unroll
  for (int q = 0; q < 16; ++q) {
    int row = m0 + (q & 3) + 8 * (q >> 2) + 4 * lh;
    float v0 = acc0[q], v1 = acc1[q];
    out[(size_t)row * 256 + n0C] = v0 > 0.f ? v0 : 0.f;
    out[(size_t)row * 256 + n1C] = v1 > 0.f ? v1 : 0.f;
  }
}

extern "C" void kernel_launch(void* const* d_in, const int* in_sizes, int n_in,
                              void* d_out, int out_size, void* d_ws, size_t ws_size,
                              hipStream_t stream) {
  const float* feats       = (const float*)d_in[0];
  const float* W1          = (const float*)d_in[1];
  const float* W2          = (const float*)d_in[2];
  const int*   batch_nodes = (const int*)d_in[3];
  const int*   neigh1      = (const int*)d_in[4];
  const int*   neigh2      = (const int*)d_in[5];
  float* out = (float*)d_out;

  unsigned short* W1s = (unsigned short*)d_ws;            // 131072 elems (swizzled)
  unsigned short* W2s = W1s + 131072;                     // 131072 elems (swizzled)
  unsigned short* A2  = W2s + 131072;                     // 8192*512 bf16 (8 MB)

  hipLaunchKernelGGL(convert_w, dim3(256), dim3(256), 0, stream, W1, W2, W1s, W2s);
  hipLaunchKernelGGL(sage_l1, dim3(M1T / 64), dim3(512), 0, stream,
                     feats, W1s, batch_nodes, neigh1, neigh2, A2);
  hipLaunchKernelGGL(sage_l2, dim3(NB / 32), dim3(256), 0, stream, A2, W2s, out);
}